// Round 7
// baseline (271.757 us; speedup 1.0000x reference)
//
#include <hip/hip_runtime.h>
#include <hip/hip_bf16.h>
#include <hip/hip_cooperative_groups.h>

namespace cg = cooperative_groups;

#define NB_MAX 8192
#define NTHR 256

// Single cooperative kernel: phases 1-4 of the cell-list build.
// Phase 1: frac/flat/pv + histogram
// Phase 2: bucket scan (block 0)        [grid.sync before]
// Phase 3: scatter + run length S + block-local offset scan
// Phase 4: blockpart scan (wave 0) + per-bucket sort/perm/pairs
__global__ __launch_bounds__(NTHR) void k_coop(
    const float* __restrict__ coord,
    const float* __restrict__ cell,
    float* __restrict__ out_frac,
    float* __restrict__ out_im,
    float* __restrict__ out_at,
    float* __restrict__ out,
    int* __restrict__ pv,
    int* __restrict__ counts,
    int* __restrict__ fill,
    int* __restrict__ scalars,
    int* __restrict__ cumc,
    int* __restrict__ pairoff,
    int* __restrict__ sorted,
    int* __restrict__ Oarr,
    int* __restrict__ blockpart,
    int* __restrict__ blockoff,
    int n) {
  cg::grid_group grid = cg::this_grid();
  __shared__ int shA[4], shB[4];
  int t = threadIdx.x;
  int lane = t & 63, wid = t >> 6;
  int a = blockIdx.x * NTHR + t;
  bool active = a < n;

  // ---- Phase 1: frac out, bucket id + packed vec, histogram ----
  int flat_r = 0, pv_r = 0;
  {
    float d0 = cell[0], d1 = cell[4], d2 = cell[8];
    const float bl = (float)(5.2 + 1e-05);
    int g0 = (int)floorf(d0 / bl) + 1;
    int g1 = (int)floorf(d1 / bl) + 1;
    int g2 = (int)floorf(d2 / bl) + 1;
    if (a == 0) {
      scalars[8] = g0; scalars[9] = g1; scalars[10] = g2;
      scalars[11] = g1 * g2; scalars[12] = g0 * g1 * g2;
    }
    if (active) {
      float x = coord[3 * a + 0], y = coord[3 * a + 1], z = coord[3 * a + 2];
      float fx = x / d0, fy = y / d1, fz = z / d2;
      out_frac[3 * a + 0] = fx;
      out_frac[3 * a + 1] = fy;
      out_frac[3 * a + 2] = fz;
      int v0 = (int)rintf(fx * (float)(g0 - 1));
      int v1 = (int)rintf(fy * (float)(g1 - 1));
      int v2 = (int)rintf(fz * (float)(g2 - 1));
      flat_r = v0 * (g1 * g2) + v1 * g1 + v2;
      pv_r = (v0 << 20) | (v1 << 10) | v2;
      pv[a] = pv_r;
      atomicAdd(&counts[flat_r], 1);
    }
  }
  grid.sync();

  // ---- Phase 2: bucket scan on block 0 (256 thr x 32 buckets) ----
  if (blockIdx.x == 0) {
    int nb = scalars[12];
    const int IT = NB_MAX / NTHR;  // 32
    int base2 = t * IT;
    int lc = 0, lp = 0;
    for (int i = 0; i < IT; ++i) {
      int idx = base2 + i;
      int c = (idx < nb) ? counts[idx] : 0;
      lc += c;
      lp += c * (c - 1) / 2;
    }
    int ic = lc, ip = lp;
    for (int off = 1; off < 64; off <<= 1) {
      int yc = __shfl_up(ic, off);
      int yp = __shfl_up(ip, off);
      if (lane >= off) { ic += yc; ip += yp; }
    }
    if (lane == 63) { shA[wid] = ic; shB[wid] = ip; }
    __syncthreads();
    if (wid == 0 && lane < 4) {
      int vc2 = shA[lane], vp2 = shB[lane];
      int sc2 = vc2, sp2 = vp2;
      for (int off = 1; off < 4; off <<= 1) {
        int yc = __shfl_up(sc2, off);
        int yp = __shfl_up(sp2, off);
        if (lane >= off) { sc2 += yc; sp2 += yp; }
      }
      shA[lane] = sc2 - vc2;
      shB[lane] = sp2 - vp2;
    }
    __syncthreads();
    int ec = shA[wid] + (ic - lc);
    int ep = shB[wid] + (ip - lp);
    for (int i = 0; i < IT; ++i) {
      int idx = base2 + i;
      int c = (idx < nb) ? counts[idx] : 0;
      if (idx < nb) { cumc[idx] = ec; pairoff[idx] = ep; }
      ec += c;
      ep += c * (c - 1) / 2;
    }
    if (t == NTHR - 1) scalars[0] = ep;  // total P
  }
  grid.sync();

  // ---- Phase 3: scatter + run length S + block-local offsets ----
  {
    int S = 0;
    if (active) {
      int pos = cumc[flat_r] + atomicAdd(&fill[flat_r], 1);
      sorted[pos] = a;
      int g0 = scalars[8], g1 = scalars[9], g2 = scalars[10], g12 = scalars[11];
      int v0 = pv_r >> 20, v1 = (pv_r >> 10) & 1023, v2 = pv_r & 1023;
#pragma unroll
      for (int m = 0; m < 7; ++m) {
        int dx = ((m >> 2) & 1) ? 0 : -1;
        int dy = ((m >> 1) & 1) ? 0 : -1;
        int dz = (m & 1) ? 0 : -1;
        int nx = v0 + dx; if (nx < 0) nx += g0;
        int ny = v1 + dy; if (ny < 0) ny += g1;
        int nz = v2 + dz; if (nz < 0) nz += g2;
        S += counts[nx * g12 + ny * g1 + nz];
      }
    }
    int iv = S;
    for (int off = 1; off < 64; off <<= 1) {
      int y = __shfl_up(iv, off);
      if (lane >= off) iv += y;
    }
    __syncthreads();   // shA reuse hazard vs phase 2 (block 0 only; others no-op)
    if (lane == 63) shA[wid] = iv;
    __syncthreads();
    if (wid == 0 && lane < 4) {
      int v2 = shA[lane], s2 = v2;
      for (int off = 1; off < 4; off <<= 1) {
        int y = __shfl_up(s2, off);
        if (lane >= off) s2 += y;
      }
      shA[lane] = s2 - v2;
      if (lane == 3) blockpart[blockIdx.x] = s2;
    }
    __syncthreads();
    if (active) Oarr[a] = shA[wid] + (iv - S);
  }
  grid.sync();

  // ---- Phase 4: blockoff scan (wave 0) + per-bucket sort/perm/pairs ----
  {
    int gw = blockIdx.x * 4 + wid;
    int nwaves = gridDim.x * 4;
    int nblocks = gridDim.x;
    if (gw == 0) {
      // exclusive scan of blockpart[0..nblocks) by one wave (lane*7 coverage=448)
      int cv[7];
      int ls = 0;
      for (int i = 0; i < 7; ++i) {
        int idx = lane * 7 + i;
        int v = (idx < nblocks) ? blockpart[idx] : 0;
        cv[i] = v;
        ls += v;
      }
      int il = ls;
      for (int off = 1; off < 64; off <<= 1) {
        int y = __shfl_up(il, off);
        if (lane >= off) il += y;
      }
      int e = il - ls;
      for (int i = 0; i < 7; ++i) {
        int idx = lane * 7 + i;
        if (idx < nblocks) blockoff[idx] = e;
        e += cv[i];
      }
    }
    int nb = scalars[12];
    int P = scalars[0];
    for (int b = gw; b < nb; b += nwaves) {
      int c = counts[b];
      if (c == 0) continue;
      int s = cumc[b];
      if (c == 1) {
        if (lane == 0) {
          int aa = sorted[s];
          out_im[s] = (float)aa;
          out_at[aa] = (float)s;
        }
        continue;
      }
      if (c <= 64) {
        int val = (lane < c) ? sorted[s + lane] : 0x7fffffff;
        int rank = 0;
        for (int j = 0; j < c; ++j) {
          int other = __shfl(val, j);
          rank += (other < val) ? 1 : 0;
        }
        if (lane < c) {
          sorted[s + rank] = val;
          out_im[s + rank] = (float)val;
          out_at[val] = (float)(s + rank);
        }
      } else if (lane == 0) {
        for (int i = 1; i < c; ++i) {
          int key = sorted[s + i];
          int j = i - 1;
          while (j >= 0 && sorted[s + j] > key) {
            sorted[s + j + 1] = sorted[s + j];
            --j;
          }
          sorted[s + j + 1] = key;
        }
        for (int i = 0; i < c; ++i) {
          int aa = sorted[s + i];
          out_im[s + i] = (float)aa;
          out_at[aa] = (float)(s + i);
        }
      }
      int off = pairoff[b];
      int np = c * (c - 1) / 2;
      for (int k = lane; k < np; k += 64) {
        int l = (int)((1.0f + sqrtf(1.0f + 8.0f * (float)k)) * 0.5f);
        while (l * (l - 1) / 2 > k) --l;
        while ((l + 1) * l / 2 <= k) ++l;
        int u = k - l * (l - 1) / 2;
        out[off + k] = (float)(s + u);
        out[P + off + k] = (float)(s + l);
      }
    }
  }
}

// K2: 16-lane-group emit of lower_between runs (coalesced stores)
__global__ void k_emit16(const int* __restrict__ pv,
                         const int* __restrict__ counts,
                         const int* __restrict__ cumc,
                         const int* __restrict__ Oarr,
                         const int* __restrict__ blockoff,
                         const int* __restrict__ scalars,
                         float* __restrict__ out, int n) {
  int gt = blockIdx.x * blockDim.x + threadIdx.x;
  int a = gt >> 4;
  int l16 = gt & 15;
  if (a >= n) return;
  int g0 = scalars[8], g1 = scalars[9], g2 = scalars[10], g12 = scalars[11];
  int p = pv[a];
  int v0 = p >> 20, v1 = (p >> 10) & 1023, v2 = p & 1023;
  int segs[8];
  int cums[7];
  segs[0] = 0;
#pragma unroll
  for (int m = 0; m < 7; ++m) {
    int dx = ((m >> 2) & 1) ? 0 : -1;
    int dy = ((m >> 1) & 1) ? 0 : -1;
    int dz = (m & 1) ? 0 : -1;
    int nx = v0 + dx; if (nx < 0) nx += g0;
    int ny = v1 + dy; if (ny < 0) ny += g1;
    int nz = v2 + dz; if (nz < 0) nz += g2;
    int nb_ = nx * g12 + ny * g1 + nz;
    cums[m] = cumc[nb_];
    segs[m + 1] = segs[m] + counts[nb_];
  }
  int S = segs[7];
  long base = 2L * (long)scalars[0] + (long)blockoff[a >> 8] + (long)Oarr[a];
  for (int q = l16; q < S; q += 16) {
    int v = cums[0] + q;
#pragma unroll
    for (int m = 1; m < 7; ++m) {
      if (q >= segs[m]) v = cums[m] + (q - segs[m]);
    }
    out[base + q] = (float)v;
  }
}

extern "C" void kernel_launch(void* const* d_in, const int* in_sizes, int n_in,
                              void* d_out, int out_size, void* d_ws, size_t ws_size,
                              hipStream_t stream) {
  const float* coord = (const float*)d_in[0];
  const float* cell = (const float*)d_in[1];
  float* out = (float*)d_out;
  int n = in_sizes[0] / 3;

  int* W = (int*)d_ws;
  int* counts = W;                         // NB_MAX
  int* fill = W + NB_MAX;                  // NB_MAX
  int* scalars = W + 2 * NB_MAX;           // 16: [0]=P [8..12]=g0,g1,g2,g1*g2,nb
  int* cumc = W + 2 * NB_MAX + 16;         // NB_MAX
  int* pairoff = cumc + NB_MAX;            // NB_MAX
  int* pv = pairoff + NB_MAX;              // n
  int* sorted = pv + n;                    // n
  int* Oarr = sorted + n;                  // n
  int* blockpart = Oarr + n;               // 1024
  int* blockoff = blockpart + 1024;        // 1024

  // output chunk bases known on host: out = [2P | L | 3n | n | n]
  float* out_frac = out + (out_size - 5 * n);
  float* out_im = out + (out_size - 2 * n);
  float* out_at = out + (out_size - n);

  int nblocks = (n + NTHR - 1) / NTHR;

  hipMemsetAsync(d_ws, 0, (size_t)(2 * NB_MAX + 16) * sizeof(int), stream);

  void* kargs[] = {
      (void*)&coord, (void*)&cell, (void*)&out_frac, (void*)&out_im,
      (void*)&out_at, (void*)&out, (void*)&pv, (void*)&counts,
      (void*)&fill, (void*)&scalars, (void*)&cumc, (void*)&pairoff,
      (void*)&sorted, (void*)&Oarr, (void*)&blockpart, (void*)&blockoff,
      (void*)&n};
  hipLaunchCooperativeKernel((void*)k_coop, dim3(nblocks), dim3(NTHR), kargs, 0, stream);

  k_emit16<<<(n * 16 + 255) / 256, 256, 0, stream>>>(pv, counts, cumc, Oarr, blockoff,
                                                     scalars, out, n);
}